// Round 2
// baseline (1089.840 us; speedup 1.0000x reference)
//
#include <hip/hip_runtime.h>

#define NB 8
#define NC 64
#define NH 256
#define NW 256
#define TW 128
#define CC 16

// Prep: fold rank loop into M^T[ci][co], bias2[co]; transpose conv weights to Wt[ci][tap][co]
__global__ __launch_bounds__(256) void prep_kernel(
    const float* __restrict__ lw, const float* __restrict__ w2a_w,
    const float* __restrict__ w2a_b, const float* __restrict__ w2b_w,
    const float* __restrict__ w2b_b, float* __restrict__ Mt,
    float* __restrict__ bias2, float* __restrict__ Wt) {
  int t = threadIdx.x;
  // Mt[i*64+o] = sum_q sum_c w2b_w[q][o][c] * w2a_w[q][c][i]
  for (int idx = t; idx < NC * NC; idx += 256) {
    int i = idx >> 6, o = idx & 63;
    float acc = 0.f;
    for (int q = 0; q < 4; ++q) {
      const float* wb = w2b_w + (q * NC + o) * NC;
      const float* wa = w2a_w + q * NC * NC + i;
      for (int c = 0; c < NC; ++c) acc += wb[c] * wa[c * NC];
    }
    Mt[idx] = acc;
  }
  if (t < NC) {
    float acc = 0.f;
    for (int q = 0; q < 4; ++q) {
      const float* wb = w2b_w + (q * NC + t) * NC;
      const float* ba = w2a_b + q * NC;
      for (int c = 0; c < NC; ++c) acc += wb[c] * ba[c];
      acc += w2b_b[q * NC + t];
    }
    bias2[t] = acc;
  }
  // Wt[(ci*9+tap)*64+co] = lw[(co*64+ci)*9+tap]
  for (int idx = t; idx < NC * 9 * NC; idx += 256) {
    int co = idx & 63;
    int tap = (idx >> 6) % 9;
    int ci = idx / (9 * 64);
    Wt[idx] = lw[(co * NC + ci) * 9 + tap];
  }
}

__global__ __launch_bounds__(256) void volterra_main(
    const float* __restrict__ x, const float* __restrict__ lb,
    const float* __restrict__ Mt, const float* __restrict__ bias2,
    const float* __restrict__ Wt, float* __restrict__ out) {
  // xt cols: col j holds pixel (w0-1+j), loaded CIRCULARLY (valid for Sn).
  __shared__ __align__(16) float xt[CC][3][TW + 8];
  __shared__ __align__(16) float snt[CC][TW];

  const int tid = threadIdx.x;
  const int wc = blockIdx.x;
  const int h = blockIdx.y;
  const int b = blockIdx.z;
  const int w0 = wc * TW;

  const int co = tid >> 2;        // 0..63
  const int wq = tid & 3;         // 0..3 -> 32 pixels each
  const int wl0 = wq * 32;

  // conv is ZERO padded: fix the two circular halo columns at true image edges
  const bool fix_lo = (w0 == 0) && (wq == 0);
  const bool fix_hi = (w0 + TW == NW) && (wq == 3);

  float acc[32];
  {
    float base = lb[co] + bias2[co];
#pragma unroll
    for (int k = 0; k < 32; ++k) acc[k] = base;
  }

  for (int cc = 0; cc < NC / CC; ++cc) {
    const int ci0 = cc * CC;
    __syncthreads();
    // stage x rows h-1..h+1 (circular), cols w0-1..w0+TW
    for (int idx = tid; idx < CC * 3 * (TW + 2); idx += 256) {
      int col = idx % (TW + 2);
      int rem = idx / (TW + 2);
      int dy = rem % 3;
      int ci = rem / 3;
      int gr = (h + dy - 1 + NH) & (NH - 1);
      int gc = (w0 - 1 + col + NW) & (NW - 1);
      xt[ci][dy][col] = x[(((size_t)b * NC + ci0 + ci) * NH + gr) * NW + gc];
    }
    __syncthreads();
    // Sn tile from the circular-halo'd xt
    for (int idx = tid; idx < CC * TW; idx += 256) {
      int ci = idx >> 7, wl = idx & (TW - 1);
      float s1 = 0.f, s2 = 0.f;
#pragma unroll
      for (int dy = 0; dy < 3; ++dy)
#pragma unroll
        for (int dx = 0; dx < 3; ++dx) {
          float v = xt[ci][dy][wl + dx];
          s1 += v;
          s2 += v * v;
        }
      snt[ci][wl] = (s1 * s1 + s2) * (0.5f / 45.0f);
    }
    __syncthreads();

    for (int ci = 0; ci < CC; ++ci) {
      const int cig = ci0 + ci;
      // F2: M * Sn
      {
        float m = Mt[cig * NC + co];
        const float4* sp = reinterpret_cast<const float4*>(&snt[ci][wl0]);
#pragma unroll
        for (int j = 0; j < 8; ++j) {
          float4 v = sp[j];
          acc[4 * j + 0] += m * v.x;
          acc[4 * j + 1] += m * v.y;
          acc[4 * j + 2] += m * v.z;
          acc[4 * j + 3] += m * v.w;
        }
      }
      // F1: conv3x3, zero padded
      const float* wtp = Wt + cig * 9 * NC + co;
#pragma unroll
      for (int dy = 0; dy < 3; ++dy) {
        if (dy == 0 && h == 0) continue;        // zero-pad row
        if (dy == 2 && h == NH - 1) continue;   // zero-pad row
        float wv0 = wtp[(dy * 3 + 0) * NC];
        float wv1 = wtp[(dy * 3 + 1) * NC];
        float wv2 = wtp[(dy * 3 + 2) * NC];
        float xr[34];
        const float4* rp = reinterpret_cast<const float4*>(&xt[ci][dy][wl0]);
#pragma unroll
        for (int j = 0; j < 8; ++j) {
          float4 v = rp[j];
          xr[4 * j + 0] = v.x;
          xr[4 * j + 1] = v.y;
          xr[4 * j + 2] = v.z;
          xr[4 * j + 3] = v.w;
        }
        xr[32] = xt[ci][dy][wl0 + 32];
        xr[33] = xt[ci][dy][wl0 + 33];
        if (fix_lo) xr[0] = 0.f;
        if (fix_hi) xr[33] = 0.f;
#pragma unroll
        for (int k = 0; k < 32; ++k) {
          acc[k] += wv0 * xr[k] + wv1 * xr[k + 1] + wv2 * xr[k + 2];
        }
      }
    }
  }

  float* op = out + (((size_t)b * NC + co) * NH + h) * NW + w0 + wl0;
#pragma unroll
  for (int j = 0; j < 8; ++j) {
    float4 v;
    v.x = acc[4 * j + 0];
    v.y = acc[4 * j + 1];
    v.z = acc[4 * j + 2];
    v.w = acc[4 * j + 3];
    reinterpret_cast<float4*>(op)[j] = v;
  }
}

extern "C" void kernel_launch(void* const* d_in, const int* in_sizes, int n_in,
                              void* d_out, int out_size, void* d_ws, size_t ws_size,
                              hipStream_t stream) {
  const float* x = (const float*)d_in[0];
  const float* lw = (const float*)d_in[1];
  const float* lb = (const float*)d_in[2];
  const float* w2a_w = (const float*)d_in[3];
  const float* w2a_b = (const float*)d_in[4];
  const float* w2b_w = (const float*)d_in[5];
  const float* w2b_b = (const float*)d_in[6];
  float* out = (float*)d_out;

  float* ws = (float*)d_ws;
  float* Mt = ws;                  // 4096 floats
  float* bias2 = ws + 4096;        // 64
  float* Wt = ws + 4096 + 64;      // 36864

  prep_kernel<<<1, 256, 0, stream>>>(lw, w2a_w, w2a_b, w2b_w, w2b_b, Mt, bias2, Wt);
  dim3 grid(NW / TW, NH, NB);
  volterra_main<<<grid, 256, 0, stream>>>(x, lb, Mt, bias2, Wt, out);
}

// Round 6
// 522.819 us; speedup vs baseline: 2.0845x; 2.0845x over previous
//
#include <hip/hip_runtime.h>

#define NB 8
#define NC 64
#define NH 256
#define NW 256

typedef short s16x8 __attribute__((ext_vector_type(8)));
typedef float f32x16 __attribute__((ext_vector_type(16)));

static __device__ __forceinline__ unsigned short f2bf(float f) {
  unsigned int u = __float_as_uint(f);
  unsigned int r = (u + 0x7fffu + ((u >> 16) & 1u)) >> 16;
  return (unsigned short)r;
}

// ---------------- fast path ----------------
// ws layout (bytes):
//   xT  [b][h][w][ci] bf16 : 0          .. 67108864
//   snT [b][h][w][ci] bf16 : 67108864   .. 134217728
//   Wg  [tap(10)][co][ci]  : 134217728  .. 134299648   (tap9 = M/90)
//   bias[64] f32           : 134299648  .. 134299904
#define WS_NEEDED 134299904ull

// Fold rank loop into tap-9 matrix; bf16-ize conv weights into [tap][co][ci].
__global__ __launch_bounds__(256) void prep_fast(
    const float* __restrict__ lw, const float* __restrict__ lb,
    const float* __restrict__ w2a_w, const float* __restrict__ w2a_b,
    const float* __restrict__ w2b_w, const float* __restrict__ w2b_b,
    unsigned short* __restrict__ Wg, float* __restrict__ bias) {
  int t = threadIdx.x;
  for (int idx = t; idx < 64 * 64 * 9; idx += 256) {
    int ci = idx & 63;
    int co = (idx >> 6) & 63;
    int tap = idx >> 12;
    Wg[idx] = f2bf(lw[(co * 64 + ci) * 9 + tap]);
  }
  for (int idx = t; idx < 64 * 64; idx += 256) {
    int ci = idx & 63, co = idx >> 6;
    float acc = 0.f;
    for (int q = 0; q < 4; ++q) {
      const float* wb = w2b_w + (q * 64 + co) * 64;
      const float* wa = w2a_w + q * 64 * 64 + ci;
      for (int c = 0; c < 64; ++c) acc += wb[c] * wa[c * 64];
    }
    Wg[9 * 4096 + idx] = f2bf(acc * (1.0f / 90.0f));
  }
  if (t < 64) {
    float acc = lb[t];
    for (int q = 0; q < 4; ++q) {
      const float* wb = w2b_w + (q * 64 + t) * 64;
      const float* ba = w2a_b + q * 64;
      for (int c = 0; c < 64; ++c) acc += wb[c] * ba[c];
      acc += w2b_b[q * 64 + t];
    }
    bias[t] = acc;
  }
}

// Stage 1: per (b,h) row: SnRaw = u^2 + v (circular 3x3 box sums of x, x^2),
// write xT and snT bf16 in [b][h][w][ci] layout (LDS transpose, coalesced out).
__global__ __launch_bounds__(256) void stage1(
    const float* __restrict__ x, unsigned short* __restrict__ xT,
    unsigned short* __restrict__ snT) {
  __shared__ __align__(16) unsigned short xb[NW * 64];
  __shared__ __align__(16) unsigned short sb[NW * 64];
  int id = blockIdx.x;
  int bid = (id & 7) * 256 + (id >> 3);   // XCD-contiguous chunks
  int b = bid >> 8, h = bid & 255;
  int w = threadIdx.x;
  int hm = (h + 255) & 255, hp = (h + 1) & 255;
  int wm = (w + 255) & 255, wp = (w + 1) & 255;
  const float* xbase = x + (size_t)b * 64 * 65536;
  char* xbc = (char*)xb;
  char* sbc = (char*)sb;
  int swz = (w & 7) << 4;
  for (int ci = 0; ci < 64; ++ci) {
    const float* p = xbase + ci * 65536;
    const float* r0 = p + hm * 256;
    const float* r1 = p + h * 256;
    const float* r2 = p + hp * 256;
    float a0 = r0[wm], a1 = r0[w], a2 = r0[wp];
    float b0 = r1[wm], b1 = r1[w], b2 = r1[wp];
    float c0 = r2[wm], c1 = r2[w], c2 = r2[wp];
    float u = a0 + a1 + a2 + b0 + b1 + b2 + c0 + c1 + c2;
    float v = a0 * a0 + a1 * a1 + a2 * a2 + b0 * b0 + b1 * b1 + b2 * b2 +
              c0 * c0 + c1 * c1 + c2 * c2;
    float sn = u * u + v;
    int off = (w * 128 + ci * 2) ^ swz;
    *(unsigned short*)(xbc + off) = f2bf(b1);
    *(unsigned short*)(sbc + off) = f2bf(sn);
  }
  __syncthreads();
  // coalesced write-out: lane pattern (row r, 16B chunk c)
  int r = threadIdx.x >> 3, c = threadIdx.x & 7;
  size_t gbase = ((size_t)(b * 256 + h) * 256) * 128;  // bytes
#pragma unroll
  for (int pass = 0; pass < 8; ++pass) {
    int rr = r + pass * 32;
    int loff = (rr * 128 + c * 16) ^ ((rr & 7) << 4);
    float4 vx = *(float4*)(xbc + loff);
    float4 vs = *(float4*)(sbc + loff);
    *(float4*)((char*)xT + gbase + rr * 128 + c * 16) = vx;
    *(float4*)((char*)snT + gbase + rr * 128 + c * 16) = vs;
  }
}

// Stage 2: implicit GEMM. D[co][px] = sum_k Wg[k][co] * A[k][px],
// K = 4 chunks x (10 taps x 16 ci). mfma_f32_32x32x16_bf16.
// Wave wv owns h-row h0+wv, 64 px, all 64 co: acc[2 m][2 n] (32co x 32px each).
#define XH_OFF 0       // x halo: 396 rows (6h x 66w) x 48B
#define SN_OFF 19008   // Sn: 256 rows (4h x 64w) x 48B
#define WL_OFF 31296   // weights, fragment-ordered: 1280 chunks x 16B
#define LDS_SZ 51776

__global__ __launch_bounds__(256, 3) void stage2(
    const unsigned short* __restrict__ xT, const unsigned short* __restrict__ snT,
    const unsigned short* __restrict__ Wg, const float* __restrict__ bias,
    float* __restrict__ out) {
  __shared__ __align__(16) char smem[LDS_SZ];
  int id = blockIdx.x;
  int bid = (id & 7) * 256 + (id >> 3);   // XCD-contiguous chunks
  int b = bid >> 8;
  int rem = bid & 255;
  int h0 = (rem >> 2) * 4, w0 = (rem & 3) * 64;
  int tid = threadIdx.x;
  int lane = tid & 63, wv = tid >> 6;
  int l31 = lane & 31, g = lane >> 5;

  f32x16 acc[2][2];
#pragma unroll
  for (int m = 0; m < 2; ++m)
#pragma unroll
    for (int n = 0; n < 2; ++n)
#pragma unroll
      for (int i = 0; i < 16; ++i) acc[m][n][i] = 0.f;

  for (int ck = 0; ck < 4; ++ck) {
    int ci0 = ck * 16;
    __syncthreads();
    // ---- stage x halo: 792 x 16B chunks, zero-pad outside image ----
    for (int idx = tid; idx < 792; idx += 256) {
      int row = idx >> 1, half = idx & 1;
      int hr = row / 66, wc = row - hr * 66;
      int gh = h0 - 1 + hr, gw = w0 - 1 + wc;
      float4 v = make_float4(0.f, 0.f, 0.f, 0.f);
      if ((unsigned)gh < 256u && (unsigned)gw < 256u)
        v = *(const float4*)((const char*)xT +
              (((size_t)(b * 256 + gh) * 256 + gw) * 64 + ci0 + half * 8) * 2);
      *(float4*)(smem + XH_OFF + row * 48 + half * 16) = v;
    }
    // ---- stage Sn: 512 chunks ----
    for (int idx = tid; idx < 512; idx += 256) {
      int row = idx >> 1, half = idx & 1;
      int ph = row >> 6, pw = row & 63;
      float4 v = *(const float4*)((const char*)snT +
            (((size_t)(b * 256 + h0 + ph) * 256 + w0 + pw) * 64 + ci0 + half * 8) * 2);
      *(float4*)(smem + SN_OFF + row * 48 + half * 16) = v;
    }
    // ---- stage weights in fragment order: 1280 chunks ----
    for (int idx = tid; idx < 1280; idx += 256) {
      int s = idx >> 7;
      int m = (idx >> 6) & 1;
      int l = idx & 63;
      float4 v = *(const float4*)((const char*)Wg +
            ((size_t)(s * 64 + m * 32 + (l & 31)) * 64 + ci0 + (l >> 5) * 8) * 2);
      *(float4*)(smem + WL_OFF + idx * 16) = v;
    }
    __syncthreads();

    // ---- 10 K-steps (taps 0..8 conv, tap 9 = Sn) ----
#pragma unroll
    for (int s = 0; s < 10; ++s) {
      s16x8 af[2], bf[2];
#pragma unroll
      for (int m = 0; m < 2; ++m)
        af[m] = *(const s16x8*)(smem + WL_OFF + ((s * 2 + m) * 64 + lane) * 16);
      if (s < 9) {
        const int dy = s / 3, dx = s - dy * 3;
        int rbase = ((wv + dy) * 66 + l31 + dx) * 48 + g * 16;
#pragma unroll
        for (int n = 0; n < 2; ++n)
          bf[n] = *(const s16x8*)(smem + XH_OFF + rbase + n * 32 * 48);
      } else {
        int rbase = (wv * 64 + l31) * 48 + g * 16;
#pragma unroll
        for (int n = 0; n < 2; ++n)
          bf[n] = *(const s16x8*)(smem + SN_OFF + rbase + n * 32 * 48);
      }
#pragma unroll
      for (int m = 0; m < 2; ++m)
#pragma unroll
        for (int n = 0; n < 2; ++n)
          acc[m][n] = __builtin_amdgcn_mfma_f32_32x32x16_bf16(af[m], bf[n],
                                                              acc[m][n], 0, 0, 0);
    }
  }

  // ---- epilogue: D row = (reg&3) + 8*(reg>>2) + 4*(lane>>5), col = lane&31 ----
  int h = h0 + wv;
#pragma unroll
  for (int m = 0; m < 2; ++m) {
#pragma unroll
    for (int reg = 0; reg < 16; ++reg) {
      int co = m * 32 + (reg & 3) + 8 * (reg >> 2) + 4 * (lane >> 5);
      float bv = bias[co];
#pragma unroll
      for (int n = 0; n < 2; ++n) {
        int w = w0 + n * 32 + l31;
        out[(((size_t)b * 64 + co) * 256 + h) * 256 + w] = acc[m][n][reg] + bv;
      }
    }
  }
}

// ---------------- fallback path (verified round-2 fp32 kernel) ----------------
#define TW 128
#define CC 16

__global__ __launch_bounds__(256) void prep_kernel(
    const float* __restrict__ lw, const float* __restrict__ w2a_w,
    const float* __restrict__ w2a_b, const float* __restrict__ w2b_w,
    const float* __restrict__ w2b_b, float* __restrict__ Mt,
    float* __restrict__ bias2, float* __restrict__ Wt) {
  int t = threadIdx.x;
  for (int idx = t; idx < NC * NC; idx += 256) {
    int i = idx >> 6, o = idx & 63;
    float acc = 0.f;
    for (int q = 0; q < 4; ++q) {
      const float* wb = w2b_w + (q * NC + o) * NC;
      const float* wa = w2a_w + q * NC * NC + i;
      for (int c = 0; c < NC; ++c) acc += wb[c] * wa[c * NC];
    }
    Mt[idx] = acc;
  }
  if (t < NC) {
    float acc = 0.f;
    for (int q = 0; q < 4; ++q) {
      const float* wb = w2b_w + (q * NC + t) * NC;
      const float* ba = w2a_b + q * NC;
      for (int c = 0; c < NC; ++c) acc += wb[c] * ba[c];
      acc += w2b_b[q * NC + t];
    }
    bias2[t] = acc;
  }
  for (int idx = t; idx < NC * 9 * NC; idx += 256) {
    int co = idx & 63;
    int tap = (idx >> 6) % 9;
    int ci = idx / (9 * 64);
    Wt[idx] = lw[(co * NC + ci) * 9 + tap];
  }
}

__global__ __launch_bounds__(256) void volterra_main(
    const float* __restrict__ x, const float* __restrict__ lb,
    const float* __restrict__ Mt, const float* __restrict__ bias2,
    const float* __restrict__ Wt, float* __restrict__ out) {
  __shared__ __align__(16) float xt[CC][3][TW + 8];
  __shared__ __align__(16) float snt[CC][TW];
  const int tid = threadIdx.x;
  const int wc = blockIdx.x;
  const int h = blockIdx.y;
  const int b = blockIdx.z;
  const int w0 = wc * TW;
  const int co = tid >> 2;
  const int wq = tid & 3;
  const int wl0 = wq * 32;
  const bool fix_lo = (w0 == 0) && (wq == 0);
  const bool fix_hi = (w0 + TW == NW) && (wq == 3);
  float acc[32];
  {
    float base = lb[co] + bias2[co];
#pragma unroll
    for (int k = 0; k < 32; ++k) acc[k] = base;
  }
  for (int cc = 0; cc < NC / CC; ++cc) {
    const int ci0 = cc * CC;
    __syncthreads();
    for (int idx = tid; idx < CC * 3 * (TW + 2); idx += 256) {
      int col = idx % (TW + 2);
      int rem = idx / (TW + 2);
      int dy = rem % 3;
      int ci = rem / 3;
      int gr = (h + dy - 1 + NH) & (NH - 1);
      int gc = (w0 - 1 + col + NW) & (NW - 1);
      xt[ci][dy][col] = x[(((size_t)b * NC + ci0 + ci) * NH + gr) * NW + gc];
    }
    __syncthreads();
    for (int idx = tid; idx < CC * TW; idx += 256) {
      int ci = idx >> 7, wl = idx & (TW - 1);
      float s1 = 0.f, s2 = 0.f;
#pragma unroll
      for (int dy = 0; dy < 3; ++dy)
#pragma unroll
        for (int dx = 0; dx < 3; ++dx) {
          float v = xt[ci][dy][wl + dx];
          s1 += v;
          s2 += v * v;
        }
      snt[ci][wl] = (s1 * s1 + s2) * (0.5f / 45.0f);
    }
    __syncthreads();
    for (int ci = 0; ci < CC; ++ci) {
      const int cig = ci0 + ci;
      {
        float m = Mt[cig * NC + co];
        const float4* sp = reinterpret_cast<const float4*>(&snt[ci][wl0]);
#pragma unroll
        for (int j = 0; j < 8; ++j) {
          float4 v = sp[j];
          acc[4 * j + 0] += m * v.x;
          acc[4 * j + 1] += m * v.y;
          acc[4 * j + 2] += m * v.z;
          acc[4 * j + 3] += m * v.w;
        }
      }
      const float* wtp = Wt + cig * 9 * NC + co;
#pragma unroll
      for (int dy = 0; dy < 3; ++dy) {
        if (dy == 0 && h == 0) continue;
        if (dy == 2 && h == NH - 1) continue;
        float wv0 = wtp[(dy * 3 + 0) * NC];
        float wv1 = wtp[(dy * 3 + 1) * NC];
        float wv2 = wtp[(dy * 3 + 2) * NC];
        float xr[34];
        const float4* rp = reinterpret_cast<const float4*>(&xt[ci][dy][wl0]);
#pragma unroll
        for (int j = 0; j < 8; ++j) {
          float4 v = rp[j];
          xr[4 * j + 0] = v.x;
          xr[4 * j + 1] = v.y;
          xr[4 * j + 2] = v.z;
          xr[4 * j + 3] = v.w;
        }
        xr[32] = xt[ci][dy][wl0 + 32];
        xr[33] = xt[ci][dy][wl0 + 33];
        if (fix_lo) xr[0] = 0.f;
        if (fix_hi) xr[33] = 0.f;
#pragma unroll
        for (int k = 0; k < 32; ++k) {
          acc[k] += wv0 * xr[k] + wv1 * xr[k + 1] + wv2 * xr[k + 2];
        }
      }
    }
  }
  float* op = out + (((size_t)b * NC + co) * NH + h) * NW + w0 + wl0;
#pragma unroll
  for (int j = 0; j < 8; ++j) {
    float4 v;
    v.x = acc[4 * j + 0];
    v.y = acc[4 * j + 1];
    v.z = acc[4 * j + 2];
    v.w = acc[4 * j + 3];
    reinterpret_cast<float4*>(op)[j] = v;
  }
}

extern "C" void kernel_launch(void* const* d_in, const int* in_sizes, int n_in,
                              void* d_out, int out_size, void* d_ws, size_t ws_size,
                              hipStream_t stream) {
  const float* x = (const float*)d_in[0];
  const float* lw = (const float*)d_in[1];
  const float* lb = (const float*)d_in[2];
  const float* w2a_w = (const float*)d_in[3];
  const float* w2a_b = (const float*)d_in[4];
  const float* w2b_w = (const float*)d_in[5];
  const float* w2b_b = (const float*)d_in[6];
  float* out = (float*)d_out;

  if (ws_size >= WS_NEEDED) {
    char* ws = (char*)d_ws;
    unsigned short* xT = (unsigned short*)(ws);
    unsigned short* snT = (unsigned short*)(ws + 67108864);
    unsigned short* Wg = (unsigned short*)(ws + 134217728);
    float* bias = (float*)(ws + 134299648);
    prep_fast<<<1, 256, 0, stream>>>(lw, lb, w2a_w, w2a_b, w2b_w, w2b_b, Wg, bias);
    stage1<<<2048, 256, 0, stream>>>(x, xT, snT);
    stage2<<<2048, 256, 0, stream>>>(xT, snT, Wg, bias, out);
  } else {
    float* ws = (float*)d_ws;
    float* Mt = ws;
    float* bias2 = ws + 4096;
    float* Wt = ws + 4096 + 64;
    prep_kernel<<<1, 256, 0, stream>>>(lw, w2a_w, w2a_b, w2b_w, w2b_b, Mt, bias2, Wt);
    dim3 grid(NW / TW, NH, NB);
    volterra_main<<<grid, 256, 0, stream>>>(x, lb, Mt, bias2, Wt, out);
  }
}

// Round 8
// 395.455 us; speedup vs baseline: 2.7559x; 1.3221x over previous
//
#include <hip/hip_runtime.h>

#define NB 8
#define NC 64
#define NH 256
#define NW 256

typedef short s16x8 __attribute__((ext_vector_type(8)));
typedef float f32x16 __attribute__((ext_vector_type(16)));

static __device__ __forceinline__ unsigned short f2bf(float f) {
  unsigned int u = __float_as_uint(f);
  unsigned int r = (u + 0x7fffu + ((u >> 16) & 1u)) >> 16;
  return (unsigned short)r;
}

// ---------------- fast path ----------------
// ws layout (bytes):
//   xT  [b][h][w][ci] bf16 : 0          .. 67108864
//   snT [b][h][w][ci] bf16 : 67108864   .. 134217728
//   Wg  [tap(10)][co][ci]  : 134217728  .. 134299648   (tap9 = M/90)
//   bias[64] f32           : 134299648  .. 134299904
#define WS_NEEDED 134299904ull

// Parallel prep: blocks 0..15 = M-fold (one thread per (ci,co), wa coalesced),
// block 16 = bias, blocks 16..63 = Wt bf16 transpose (strided).
__global__ __launch_bounds__(256) void prep_fast(
    const float* __restrict__ lw, const float* __restrict__ lb,
    const float* __restrict__ w2a_w, const float* __restrict__ w2a_b,
    const float* __restrict__ w2b_w, const float* __restrict__ w2b_b,
    unsigned short* __restrict__ Wg, float* __restrict__ bias) {
  int blk = blockIdx.x;
  int t = threadIdx.x;
  if (blk < 16) {
    // Mt[co][ci] = sum_q sum_c w2b_w[q][co][c] * w2a_w[q][c][ci], scaled 1/90
    int gidx = blk * 256 + t;
    int ci = gidx & 63, co = gidx >> 6;
    float acc = 0.f;
    for (int q = 0; q < 4; ++q) {
      const float* wb = w2b_w + (q * 64 + co) * 64;
      const float* wa = w2a_w + q * 4096 + ci;
      for (int c = 0; c < 64; ++c) acc += wb[c] * wa[c * 64];
    }
    Wg[9 * 4096 + co * 64 + ci] = f2bf(acc * (1.0f / 90.0f));
    return;
  }
  // Wt transpose: Wg[tap][co][ci] = lw[(co*64+ci)*9+tap], 36864 elems over 48 blocks
  for (int idx = (blk - 16) * 256 + t; idx < 64 * 64 * 9; idx += 48 * 256) {
    int ci = idx & 63;
    int co = (idx >> 6) & 63;
    int tap = idx >> 12;
    Wg[idx] = f2bf(lw[(co * 64 + ci) * 9 + tap]);
  }
  if (blk == 16 && t < 64) {
    float acc = lb[t];
    for (int q = 0; q < 4; ++q) {
      const float* wb = w2b_w + (q * 64 + t) * 64;
      const float* ba = w2a_b + q * 64;
      for (int c = 0; c < 64; ++c) acc += wb[c] * ba[c];
      acc += w2b_b[q * 64 + t];
    }
    bias[t] = acc;
  }
}

// Stage 1 v2: per (b,h) row. 512 threads: w = tid&255, ci-half = tid>>8.
// Each thread processes 32 ci as 16 pairs (18 loads in flight, u32-packed
// LDS writes). SnRaw = u^2 + v (circular 3x3 sums); bf16 x and Sn written
// to [b][h][w][ci] via LDS transpose, coalesced float4 out.
__global__ __launch_bounds__(512, 4) void stage1(
    const float* __restrict__ x, unsigned short* __restrict__ xT,
    unsigned short* __restrict__ snT) {
  __shared__ __align__(16) unsigned short xb[NW * 64];
  __shared__ __align__(16) unsigned short sb[NW * 64];
  int id = blockIdx.x;
  int bid = (id & 7) * 256 + (id >> 3);   // XCD-contiguous chunks
  int b = bid >> 8, h = bid & 255;
  int tid = threadIdx.x;
  int w = tid & 255;
  int ciBase = (tid >> 8) * 32;
  int hm = (h + 255) & 255, hp = (h + 1) & 255;
  int wm = (w + 255) & 255, wp = (w + 1) & 255;
  const float* xbase = x + (size_t)b * 64 * 65536;
  char* xbc = (char*)xb;
  char* sbc = (char*)sb;
  int swz = (w & 7) << 4;
  int rowm = hm * 256, row0 = h * 256, rowp = hp * 256;
  for (int i = 0; i < 16; ++i) {
    int ci = ciBase + i * 2;
    const float* p0 = xbase + (size_t)ci * 65536;
    const float* p1 = p0 + 65536;
    float a0 = p0[rowm + wm], a1 = p0[rowm + w], a2 = p0[rowm + wp];
    float b0 = p0[row0 + wm], b1 = p0[row0 + w], b2 = p0[row0 + wp];
    float c0 = p0[rowp + wm], c1 = p0[rowp + w], c2 = p0[rowp + wp];
    float d0 = p1[rowm + wm], d1 = p1[rowm + w], d2 = p1[rowm + wp];
    float e0 = p1[row0 + wm], e1 = p1[row0 + w], e2 = p1[row0 + wp];
    float f0 = p1[rowp + wm], f1 = p1[rowp + w], f2 = p1[rowp + wp];
    float u0 = a0 + a1 + a2 + b0 + b1 + b2 + c0 + c1 + c2;
    float v0 = a0 * a0 + a1 * a1 + a2 * a2 + b0 * b0 + b1 * b1 + b2 * b2 +
               c0 * c0 + c1 * c1 + c2 * c2;
    float u1 = d0 + d1 + d2 + e0 + e1 + e2 + f0 + f1 + f2;
    float v1 = d0 * d0 + d1 * d1 + d2 * d2 + e0 * e0 + e1 * e1 + e2 * e2 +
               f0 * f0 + f1 * f1 + f2 * f2;
    float sn0 = u0 * u0 + v0;
    float sn1 = u1 * u1 + v1;
    unsigned int xp = (unsigned int)f2bf(b1) | ((unsigned int)f2bf(e1) << 16);
    unsigned int sp = (unsigned int)f2bf(sn0) | ((unsigned int)f2bf(sn1) << 16);
    int off = (w * 128 + ci * 2) ^ swz;  // XOR is 16B-chunk level: u32 stays intact
    *(unsigned int*)(xbc + off) = xp;
    *(unsigned int*)(sbc + off) = sp;
  }
  __syncthreads();
  // coalesced write-out: 512 threads, 4 passes over 256 rows
  int r = tid >> 3, c = tid & 7;
  size_t gbase = ((size_t)(b * 256 + h) * 256) * 128;  // bytes
#pragma unroll
  for (int pass = 0; pass < 4; ++pass) {
    int rr = r + pass * 64;
    int loff = (rr * 128 + c * 16) ^ ((rr & 7) << 4);
    float4 vx = *(float4*)(xbc + loff);
    float4 vs = *(float4*)(sbc + loff);
    *(float4*)((char*)xT + gbase + rr * 128 + c * 16) = vx;
    *(float4*)((char*)snT + gbase + rr * 128 + c * 16) = vs;
  }
}

// Stage 2: implicit GEMM. D[co][px] = sum_k Wg[k][co] * A[k][px],
// K = 4 chunks x (10 taps x 16 ci). mfma_f32_32x32x16_bf16.
// Wave wv owns h-row h0+wv, 64 px, all 64 co: acc[2 m][2 n] (32co x 32px each).
#define XH_OFF 0       // x halo: 396 rows (6h x 66w) x 48B
#define SN_OFF 19008   // Sn: 256 rows (4h x 64w) x 48B
#define WL_OFF 31296   // weights, fragment-ordered: 1280 chunks x 16B
#define LDS_SZ 51776

__global__ __launch_bounds__(256, 3) void stage2(
    const unsigned short* __restrict__ xT, const unsigned short* __restrict__ snT,
    const unsigned short* __restrict__ Wg, const float* __restrict__ bias,
    float* __restrict__ out) {
  __shared__ __align__(16) char smem[LDS_SZ];
  int id = blockIdx.x;
  int bid = (id & 7) * 256 + (id >> 3);   // XCD-contiguous chunks
  int b = bid >> 8;
  int rem = bid & 255;
  int h0 = (rem >> 2) * 4, w0 = (rem & 3) * 64;
  int tid = threadIdx.x;
  int lane = tid & 63, wv = tid >> 6;
  int l31 = lane & 31, g = lane >> 5;

  f32x16 acc[2][2];
#pragma unroll
  for (int m = 0; m < 2; ++m)
#pragma unroll
    for (int n = 0; n < 2; ++n)
#pragma unroll
      for (int i = 0; i < 16; ++i) acc[m][n][i] = 0.f;

  for (int ck = 0; ck < 4; ++ck) {
    int ci0 = ck * 16;
    __syncthreads();
    // ---- stage x halo: 792 x 16B chunks, zero-pad outside image ----
    for (int idx = tid; idx < 792; idx += 256) {
      int row = idx >> 1, half = idx & 1;
      int hr = row / 66, wc = row - hr * 66;
      int gh = h0 - 1 + hr, gw = w0 - 1 + wc;
      float4 v = make_float4(0.f, 0.f, 0.f, 0.f);
      if ((unsigned)gh < 256u && (unsigned)gw < 256u)
        v = *(const float4*)((const char*)xT +
              (((size_t)(b * 256 + gh) * 256 + gw) * 64 + ci0 + half * 8) * 2);
      *(float4*)(smem + XH_OFF + row * 48 + half * 16) = v;
    }
    // ---- stage Sn: 512 chunks ----
    for (int idx = tid; idx < 512; idx += 256) {
      int row = idx >> 1, half = idx & 1;
      int ph = row >> 6, pw = row & 63;
      float4 v = *(const float4*)((const char*)snT +
            (((size_t)(b * 256 + h0 + ph) * 256 + w0 + pw) * 64 + ci0 + half * 8) * 2);
      *(float4*)(smem + SN_OFF + row * 48 + half * 16) = v;
    }
    // ---- stage weights in fragment order: 1280 chunks ----
    for (int idx = tid; idx < 1280; idx += 256) {
      int s = idx >> 7;
      int m = (idx >> 6) & 1;
      int l = idx & 63;
      float4 v = *(const float4*)((const char*)Wg +
            ((size_t)(s * 64 + m * 32 + (l & 31)) * 64 + ci0 + (l >> 5) * 8) * 2);
      *(float4*)(smem + WL_OFF + idx * 16) = v;
    }
    __syncthreads();

    // ---- 10 K-steps (taps 0..8 conv, tap 9 = Sn) ----
#pragma unroll
    for (int s = 0; s < 10; ++s) {
      s16x8 af[2], bf[2];
#pragma unroll
      for (int m = 0; m < 2; ++m)
        af[m] = *(const s16x8*)(smem + WL_OFF + ((s * 2 + m) * 64 + lane) * 16);
      if (s < 9) {
        const int dy = s / 3, dx = s - dy * 3;
        int rbase = ((wv + dy) * 66 + l31 + dx) * 48 + g * 16;
#pragma unroll
        for (int n = 0; n < 2; ++n)
          bf[n] = *(const s16x8*)(smem + XH_OFF + rbase + n * 32 * 48);
      } else {
        int rbase = (wv * 64 + l31) * 48 + g * 16;
#pragma unroll
        for (int n = 0; n < 2; ++n)
          bf[n] = *(const s16x8*)(smem + SN_OFF + rbase + n * 32 * 48);
      }
#pragma unroll
      for (int m = 0; m < 2; ++m)
#pragma unroll
        for (int n = 0; n < 2; ++n)
          acc[m][n] = __builtin_amdgcn_mfma_f32_32x32x16_bf16(af[m], bf[n],
                                                              acc[m][n], 0, 0, 0);
    }
  }

  // ---- epilogue: D row = (reg&3) + 8*(reg>>2) + 4*(lane>>5), col = lane&31 ----
  int h = h0 + wv;
#pragma unroll
  for (int m = 0; m < 2; ++m) {
#pragma unroll
    for (int reg = 0; reg < 16; ++reg) {
      int co = m * 32 + (reg & 3) + 8 * (reg >> 2) + 4 * (lane >> 5);
      float bv = bias[co];
#pragma unroll
      for (int n = 0; n < 2; ++n) {
        int w = w0 + n * 32 + l31;
        out[(((size_t)b * 64 + co) * 256 + h) * 256 + w] = acc[m][n][reg] + bv;
      }
    }
  }
}

// ---------------- fallback path (verified round-2 fp32 kernel) ----------------
#define TW 128
#define CC 16

__global__ __launch_bounds__(256) void prep_kernel(
    const float* __restrict__ lw, const float* __restrict__ w2a_w,
    const float* __restrict__ w2a_b, const float* __restrict__ w2b_w,
    const float* __restrict__ w2b_b, float* __restrict__ Mt,
    float* __restrict__ bias2, float* __restrict__ Wt) {
  int t = threadIdx.x;
  for (int idx = t; idx < NC * NC; idx += 256) {
    int i = idx >> 6, o = idx & 63;
    float acc = 0.f;
    for (int q = 0; q < 4; ++q) {
      const float* wb = w2b_w + (q * NC + o) * NC;
      const float* wa = w2a_w + q * NC * NC + i;
      for (int c = 0; c < NC; ++c) acc += wb[c] * wa[c * NC];
    }
    Mt[idx] = acc;
  }
  if (t < NC) {
    float acc = 0.f;
    for (int q = 0; q < 4; ++q) {
      const float* wb = w2b_w + (q * NC + t) * NC;
      const float* ba = w2a_b + q * NC;
      for (int c = 0; c < NC; ++c) acc += wb[c] * ba[c];
      acc += w2b_b[q * NC + t];
    }
    bias2[t] = acc;
  }
  for (int idx = t; idx < NC * 9 * NC; idx += 256) {
    int co = idx & 63;
    int tap = (idx >> 6) % 9;
    int ci = idx / (9 * 64);
    Wt[idx] = lw[(co * NC + ci) * 9 + tap];
  }
}

__global__ __launch_bounds__(256) void volterra_main(
    const float* __restrict__ x, const float* __restrict__ lb,
    const float* __restrict__ Mt, const float* __restrict__ bias2,
    const float* __restrict__ Wt, float* __restrict__ out) {
  __shared__ __align__(16) float xt[CC][3][TW + 8];
  __shared__ __align__(16) float snt[CC][TW];
  const int tid = threadIdx.x;
  const int wc = blockIdx.x;
  const int h = blockIdx.y;
  const int b = blockIdx.z;
  const int w0 = wc * TW;
  const int co = tid >> 2;
  const int wq = tid & 3;
  const int wl0 = wq * 32;
  const bool fix_lo = (w0 == 0) && (wq == 0);
  const bool fix_hi = (w0 + TW == NW) && (wq == 3);
  float acc[32];
  {
    float base = lb[co] + bias2[co];
#pragma unroll
    for (int k = 0; k < 32; ++k) acc[k] = base;
  }
  for (int cc = 0; cc < NC / CC; ++cc) {
    const int ci0 = cc * CC;
    __syncthreads();
    for (int idx = tid; idx < CC * 3 * (TW + 2); idx += 256) {
      int col = idx % (TW + 2);
      int rem = idx / (TW + 2);
      int dy = rem % 3;
      int ci = rem / 3;
      int gr = (h + dy - 1 + NH) & (NH - 1);
      int gc = (w0 - 1 + col + NW) & (NW - 1);
      xt[ci][dy][col] = x[(((size_t)b * NC + ci0 + ci) * NH + gr) * NW + gc];
    }
    __syncthreads();
    for (int idx = tid; idx < CC * TW; idx += 256) {
      int ci = idx >> 7, wl = idx & (TW - 1);
      float s1 = 0.f, s2 = 0.f;
#pragma unroll
      for (int dy = 0; dy < 3; ++dy)
#pragma unroll
        for (int dx = 0; dx < 3; ++dx) {
          float v = xt[ci][dy][wl + dx];
          s1 += v;
          s2 += v * v;
        }
      snt[ci][wl] = (s1 * s1 + s2) * (0.5f / 45.0f);
    }
    __syncthreads();
    for (int ci = 0; ci < CC; ++ci) {
      const int cig = ci0 + ci;
      {
        float m = Mt[cig * NC + co];
        const float4* sp = reinterpret_cast<const float4*>(&snt[ci][wl0]);
#pragma unroll
        for (int j = 0; j < 8; ++j) {
          float4 v = sp[j];
          acc[4 * j + 0] += m * v.x;
          acc[4 * j + 1] += m * v.y;
          acc[4 * j + 2] += m * v.z;
          acc[4 * j + 3] += m * v.w;
        }
      }
      const float* wtp = Wt + cig * 9 * NC + co;
#pragma unroll
      for (int dy = 0; dy < 3; ++dy) {
        if (dy == 0 && h == 0) continue;
        if (dy == 2 && h == NH - 1) continue;
        float wv0 = wtp[(dy * 3 + 0) * NC];
        float wv1 = wtp[(dy * 3 + 1) * NC];
        float wv2 = wtp[(dy * 3 + 2) * NC];
        float xr[34];
        const float4* rp = reinterpret_cast<const float4*>(&xt[ci][dy][wl0]);
#pragma unroll
        for (int j = 0; j < 8; ++j) {
          float4 v = rp[j];
          xr[4 * j + 0] = v.x;
          xr[4 * j + 1] = v.y;
          xr[4 * j + 2] = v.z;
          xr[4 * j + 3] = v.w;
        }
        xr[32] = xt[ci][dy][wl0 + 32];
        xr[33] = xt[ci][dy][wl0 + 33];
        if (fix_lo) xr[0] = 0.f;
        if (fix_hi) xr[33] = 0.f;
#pragma unroll
        for (int k = 0; k < 32; ++k) {
          acc[k] += wv0 * xr[k] + wv1 * xr[k + 1] + wv2 * xr[k + 2];
        }
      }
    }
  }
  float* op = out + (((size_t)b * NC + co) * NH + h) * NW + w0 + wl0;
#pragma unroll
  for (int j = 0; j < 8; ++j) {
    float4 v;
    v.x = acc[4 * j + 0];
    v.y = acc[4 * j + 1];
    v.z = acc[4 * j + 2];
    v.w = acc[4 * j + 3];
    reinterpret_cast<float4*>(op)[j] = v;
  }
}

extern "C" void kernel_launch(void* const* d_in, const int* in_sizes, int n_in,
                              void* d_out, int out_size, void* d_ws, size_t ws_size,
                              hipStream_t stream) {
  const float* x = (const float*)d_in[0];
  const float* lw = (const float*)d_in[1];
  const float* lb = (const float*)d_in[2];
  const float* w2a_w = (const float*)d_in[3];
  const float* w2a_b = (const float*)d_in[4];
  const float* w2b_w = (const float*)d_in[5];
  const float* w2b_b = (const float*)d_in[6];
  float* out = (float*)d_out;

  if (ws_size >= WS_NEEDED) {
    char* ws = (char*)d_ws;
    unsigned short* xT = (unsigned short*)(ws);
    unsigned short* snT = (unsigned short*)(ws + 67108864);
    unsigned short* Wg = (unsigned short*)(ws + 134217728);
    float* bias = (float*)(ws + 134299648);
    prep_fast<<<64, 256, 0, stream>>>(lw, lb, w2a_w, w2a_b, w2b_w, w2b_b, Wg, bias);
    stage1<<<2048, 512, 0, stream>>>(x, xT, snT);
    stage2<<<2048, 256, 0, stream>>>(xT, snT, Wg, bias, out);
  } else {
    float* ws = (float*)d_ws;
    float* Mt = ws;
    float* bias2 = ws + 4096;
    float* Wt = ws + 4096 + 64;
    prep_kernel<<<1, 256, 0, stream>>>(lw, w2a_w, w2a_b, w2b_w, w2b_b, Mt, bias2, Wt);
    dim3 grid(NW / TW, NH, NB);
    volterra_main<<<grid, 256, 0, stream>>>(x, lb, Mt, bias2, Wt, out);
  }
}

// Round 9
// 365.928 us; speedup vs baseline: 2.9783x; 1.0807x over previous
//
#include <hip/hip_runtime.h>

#define NB 8
#define NC 64
#define NH 256
#define NW 256

typedef short s16x8 __attribute__((ext_vector_type(8)));
typedef float f32x16 __attribute__((ext_vector_type(16)));

static __device__ __forceinline__ unsigned short f2bf(float f) {
  unsigned int u = __float_as_uint(f);
  unsigned int r = (u + 0x7fffu + ((u >> 16) & 1u)) >> 16;
  return (unsigned short)r;
}

// ---------------- fast path ----------------
// ws layout (bytes), CHUNK-MAJOR intermediates (ck = ci>>4):
//   xCk [ck][b][h][w][16ci] bf16 : 0          .. 67108864   (4 x 16 MB regions)
//   snCk[ck][b][h][w][16ci] bf16 : 67108864   .. 134217728
//   Wf  [ck][s(10)][m(2)][lane(64)][8ci] bf16 : 134217728 .. 134299648  (fragment-ordered)
//   bias[64] f32                  : 134299648 .. 134299904
#define WS_NEEDED 134299904ull
#define CKSTRIDE 16777216ull   // bytes per ck region (8*65536 px * 32 B)

static __device__ __forceinline__ int wfoff(int tap, int co, int ci) {
  // fragment order: [ck][tap][m][lane][j]; lane = (cihi<<5)|(co&31), j = ci&7
  int ck = ci >> 4;
  int lane = (((ci >> 3) & 1) << 5) | (co & 31);
  int m = co >> 5;
  return ((((ck * 10 + tap) * 2 + m) * 64 + lane) << 3) | (ci & 7);
}

// Parallel prep: blocks 0..15 = M-fold (tap 9), block 16 = bias,
// blocks 16..63 = conv-weight bf16 transpose. All writes fragment-ordered.
__global__ __launch_bounds__(256) void prep_fast(
    const float* __restrict__ lw, const float* __restrict__ lb,
    const float* __restrict__ w2a_w, const float* __restrict__ w2a_b,
    const float* __restrict__ w2b_w, const float* __restrict__ w2b_b,
    unsigned short* __restrict__ Wf, float* __restrict__ bias) {
  int blk = blockIdx.x;
  int t = threadIdx.x;
  if (blk < 16) {
    // M[co][ci] = sum_q sum_c w2b_w[q][co][c] * w2a_w[q][c][ci], scaled 1/90
    int gidx = blk * 256 + t;
    int ci = gidx & 63, co = gidx >> 6;
    float acc = 0.f;
    for (int q = 0; q < 4; ++q) {
      const float* wb = w2b_w + (q * 64 + co) * 64;
      const float* wa = w2a_w + q * 4096 + ci;
      for (int c = 0; c < 64; ++c) acc += wb[c] * wa[c * 64];
    }
    Wf[wfoff(9, co, ci)] = f2bf(acc * (1.0f / 90.0f));
    return;
  }
  for (int idx = (blk - 16) * 256 + t; idx < 64 * 64 * 9; idx += 48 * 256) {
    int ci = idx & 63;
    int co = (idx >> 6) & 63;
    int tap = idx >> 12;
    Wf[wfoff(tap, co, ci)] = f2bf(lw[(co * 64 + ci) * 9 + tap]);
  }
  if (blk == 16 && t < 64) {
    float acc = lb[t];
    for (int q = 0; q < 4; ++q) {
      const float* wb = w2b_w + (q * 64 + t) * 64;
      const float* ba = w2a_b + q * 64;
      for (int c = 0; c < 64; ++c) acc += wb[c] * ba[c];
      acc += w2b_b[q * 64 + t];
    }
    bias[t] = acc;
  }
}

// Stage 1: per (b,h) row. 512 threads: w = tid&255, ci-half = tid>>8.
// Each thread: 32 ci as 16 pairs (ILP), u32-packed LDS writes. SnRaw = u^2+v
// (circular 3x3 sums). Write-out to CHUNK-MAJOR regions, float4 coalesced.
__global__ __launch_bounds__(512, 4) void stage1(
    const float* __restrict__ x, unsigned short* __restrict__ xT,
    unsigned short* __restrict__ snT) {
  __shared__ __align__(16) unsigned short xb[NW * 64];
  __shared__ __align__(16) unsigned short sb[NW * 64];
  int id = blockIdx.x;
  int bid = (id & 7) * 256 + (id >> 3);   // XCD-contiguous chunks
  int b = bid >> 8, h = bid & 255;
  int tid = threadIdx.x;
  int w = tid & 255;
  int ciBase = (tid >> 8) * 32;
  int hm = (h + 255) & 255, hp = (h + 1) & 255;
  int wm = (w + 255) & 255, wp = (w + 1) & 255;
  const float* xbase = x + (size_t)b * 64 * 65536;
  char* xbc = (char*)xb;
  char* sbc = (char*)sb;
  int swz = (w & 7) << 4;
  int rowm = hm * 256, row0 = h * 256, rowp = hp * 256;
  for (int i = 0; i < 16; ++i) {
    int ci = ciBase + i * 2;
    const float* p0 = xbase + (size_t)ci * 65536;
    const float* p1 = p0 + 65536;
    float a0 = p0[rowm + wm], a1 = p0[rowm + w], a2 = p0[rowm + wp];
    float b0 = p0[row0 + wm], b1 = p0[row0 + w], b2 = p0[row0 + wp];
    float c0 = p0[rowp + wm], c1 = p0[rowp + w], c2 = p0[rowp + wp];
    float d0 = p1[rowm + wm], d1 = p1[rowm + w], d2 = p1[rowm + wp];
    float e0 = p1[row0 + wm], e1 = p1[row0 + w], e2 = p1[row0 + wp];
    float f0 = p1[rowp + wm], f1 = p1[rowp + w], f2 = p1[rowp + wp];
    float u0 = a0 + a1 + a2 + b0 + b1 + b2 + c0 + c1 + c2;
    float v0 = a0 * a0 + a1 * a1 + a2 * a2 + b0 * b0 + b1 * b1 + b2 * b2 +
               c0 * c0 + c1 * c1 + c2 * c2;
    float u1 = d0 + d1 + d2 + e0 + e1 + e2 + f0 + f1 + f2;
    float v1 = d0 * d0 + d1 * d1 + d2 * d2 + e0 * e0 + e1 * e1 + e2 * e2 +
               f0 * f0 + f1 * f1 + f2 * f2;
    float sn0 = u0 * u0 + v0;
    float sn1 = u1 * u1 + v1;
    unsigned int xp = (unsigned int)f2bf(b1) | ((unsigned int)f2bf(e1) << 16);
    unsigned int sp = (unsigned int)f2bf(sn0) | ((unsigned int)f2bf(sn1) << 16);
    int off = (w * 128 + ci * 2) ^ swz;  // XOR touches only bits 4..6: u32 intact
    *(unsigned int*)(xbc + off) = xp;
    *(unsigned int*)(sbc + off) = sp;
  }
  __syncthreads();
  // coalesced write-out to chunk-major regions: c = 16B chunk -> ck = c>>1, half = c&1
  int r = tid >> 3, c = tid & 7;
  int ck = c >> 1, half = c & 1;
  size_t pbase = (size_t)b * 65536 + (size_t)h * 256;  // pixel index base
  char* xdst = (char*)xT + (size_t)ck * CKSTRIDE + half * 16;
  char* sdst = (char*)snT + (size_t)ck * CKSTRIDE + half * 16;
#pragma unroll
  for (int pass = 0; pass < 4; ++pass) {
    int rr = r + pass * 64;
    int loff = (rr * 128 + c * 16) ^ ((rr & 7) << 4);
    float4 vx = *(float4*)(xbc + loff);
    float4 vs = *(float4*)(sbc + loff);
    *(float4*)(xdst + (pbase + rr) * 32) = vx;
    *(float4*)(sdst + (pbase + rr) * 32) = vs;
  }
}

// Stage 2: implicit GEMM. D[co][px] = sum_k Wf[k][co] * B[k][px],
// K = 4 chunks x (10 taps x 16 ci). mfma_f32_32x32x16_bf16.
// Chunk-major intermediates -> dense sequential 32B/pixel reads.
#define XH_OFF 0       // x halo: 396 rows (6h x 66w) x 48B
#define SN_OFF 19008   // Sn: 256 rows (4h x 64w) x 48B
#define WL_OFF 31296   // weights: 1280 chunks x 16B (contiguous copy of Wf[ck])
#define LDS_SZ 51776

__global__ __launch_bounds__(256, 3) void stage2(
    const unsigned short* __restrict__ xT, const unsigned short* __restrict__ snT,
    const unsigned short* __restrict__ Wf, const float* __restrict__ bias,
    float* __restrict__ out) {
  __shared__ __align__(16) char smem[LDS_SZ];
  int id = blockIdx.x;
  int bid = (id & 7) * 256 + (id >> 3);   // XCD-contiguous chunks
  int b = bid >> 8;
  int rem = bid & 255;
  int h0 = (rem >> 2) * 4, w0 = (rem & 3) * 64;
  int tid = threadIdx.x;
  int lane = tid & 63, wv = tid >> 6;
  int l31 = lane & 31, g = lane >> 5;

  f32x16 acc[2][2];
#pragma unroll
  for (int m = 0; m < 2; ++m)
#pragma unroll
    for (int n = 0; n < 2; ++n)
#pragma unroll
      for (int i = 0; i < 16; ++i) acc[m][n][i] = 0.f;

  for (int ck = 0; ck < 4; ++ck) {
    const char* xsrc = (const char*)xT + (size_t)ck * CKSTRIDE;
    const char* ssrc = (const char*)snT + (size_t)ck * CKSTRIDE;
    const char* wsrc = (const char*)Wf + ck * 20480;
    __syncthreads();
    // ---- stage x halo: 792 x 16B chunks, zero-pad outside image ----
    for (int idx = tid; idx < 792; idx += 256) {
      int row = idx >> 1, half = idx & 1;
      int hr = row / 66, wc = row - hr * 66;
      int gh = h0 - 1 + hr, gw = w0 - 1 + wc;
      float4 v = make_float4(0.f, 0.f, 0.f, 0.f);
      if ((unsigned)gh < 256u && (unsigned)gw < 256u)
        v = *(const float4*)(xsrc +
              ((size_t)b * 65536 + gh * 256 + gw) * 32 + half * 16);
      *(float4*)(smem + XH_OFF + row * 48 + half * 16) = v;
    }
    // ---- stage Sn: 512 chunks, dense ----
    for (int idx = tid; idx < 512; idx += 256) {
      int row = idx >> 1, half = idx & 1;
      int ph = row >> 6, pw = row & 63;
      float4 v = *(const float4*)(ssrc +
            ((size_t)b * 65536 + (h0 + ph) * 256 + w0 + pw) * 32 + half * 16);
      *(float4*)(smem + SN_OFF + row * 48 + half * 16) = v;
    }
    // ---- stage weights: contiguous 20 KB copy ----
    for (int idx = tid; idx < 1280; idx += 256) {
      float4 v = *(const float4*)(wsrc + idx * 16);
      *(float4*)(smem + WL_OFF + idx * 16) = v;
    }
    __syncthreads();

    // ---- 10 K-steps (taps 0..8 conv, tap 9 = Sn) ----
#pragma unroll
    for (int s = 0; s < 10; ++s) {
      s16x8 af[2], bf[2];
#pragma unroll
      for (int m = 0; m < 2; ++m)
        af[m] = *(const s16x8*)(smem + WL_OFF + ((s * 2 + m) * 64 + lane) * 16);
      if (s < 9) {
        const int dy = s / 3, dx = s - dy * 3;
        int rbase = ((wv + dy) * 66 + l31 + dx) * 48 + g * 16;
#pragma unroll
        for (int n = 0; n < 2; ++n)
          bf[n] = *(const s16x8*)(smem + XH_OFF + rbase + n * 32 * 48);
      } else {
        int rbase = (wv * 64 + l31) * 48 + g * 16;
#pragma unroll
        for (int n = 0; n < 2; ++n)
          bf[n] = *(const s16x8*)(smem + SN_OFF + rbase + n * 32 * 48);
      }
#pragma unroll
      for (int m = 0; m < 2; ++m)
#pragma unroll
        for (int n = 0; n < 2; ++n)
          acc[m][n] = __builtin_amdgcn_mfma_f32_32x32x16_bf16(af[m], bf[n],
                                                              acc[m][n], 0, 0, 0);
    }
  }

  // ---- epilogue: D row = (reg&3) + 8*(reg>>2) + 4*(lane>>5), col = lane&31 ----
  int h = h0 + wv;
#pragma unroll
  for (int m = 0; m < 2; ++m) {
#pragma unroll
    for (int reg = 0; reg < 16; ++reg) {
      int co = m * 32 + (reg & 3) + 8 * (reg >> 2) + 4 * (lane >> 5);
      float bv = bias[co];
#pragma unroll
      for (int n = 0; n < 2; ++n) {
        int w = w0 + n * 32 + l31;
        out[(((size_t)b * 64 + co) * 256 + h) * 256 + w] = acc[m][n][reg] + bv;
      }
    }
  }
}

// ---------------- fallback path (verified round-2 fp32 kernel) ----------------
#define TW 128
#define CC 16

__global__ __launch_bounds__(256) void prep_kernel(
    const float* __restrict__ lw, const float* __restrict__ w2a_w,
    const float* __restrict__ w2a_b, const float* __restrict__ w2b_w,
    const float* __restrict__ w2b_b, float* __restrict__ Mt,
    float* __restrict__ bias2, float* __restrict__ Wt) {
  int t = threadIdx.x;
  for (int idx = t; idx < NC * NC; idx += 256) {
    int i = idx >> 6, o = idx & 63;
    float acc = 0.f;
    for (int q = 0; q < 4; ++q) {
      const float* wb = w2b_w + (q * NC + o) * NC;
      const float* wa = w2a_w + q * NC * NC + i;
      for (int c = 0; c < NC; ++c) acc += wb[c] * wa[c * NC];
    }
    Mt[idx] = acc;
  }
  if (t < NC) {
    float acc = 0.f;
    for (int q = 0; q < 4; ++q) {
      const float* wb = w2b_w + (q * NC + t) * NC;
      const float* ba = w2a_b + q * NC;
      for (int c = 0; c < NC; ++c) acc += wb[c] * ba[c];
      acc += w2b_b[q * NC + t];
    }
    bias2[t] = acc;
  }
  for (int idx = t; idx < NC * 9 * NC; idx += 256) {
    int co = idx & 63;
    int tap = (idx >> 6) % 9;
    int ci = idx / (9 * 64);
    Wt[idx] = lw[(co * NC + ci) * 9 + tap];
  }
}

__global__ __launch_bounds__(256) void volterra_main(
    const float* __restrict__ x, const float* __restrict__ lb,
    const float* __restrict__ Mt, const float* __restrict__ bias2,
    const float* __restrict__ Wt, float* __restrict__ out) {
  __shared__ __align__(16) float xt[CC][3][TW + 8];
  __shared__ __align__(16) float snt[CC][TW];
  const int tid = threadIdx.x;
  const int wc = blockIdx.x;
  const int h = blockIdx.y;
  const int b = blockIdx.z;
  const int w0 = wc * TW;
  const int co = tid >> 2;
  const int wq = tid & 3;
  const int wl0 = wq * 32;
  const bool fix_lo = (w0 == 0) && (wq == 0);
  const bool fix_hi = (w0 + TW == NW) && (wq == 3);
  float acc[32];
  {
    float base = lb[co] + bias2[co];
#pragma unroll
    for (int k = 0; k < 32; ++k) acc[k] = base;
  }
  for (int cc = 0; cc < NC / CC; ++cc) {
    const int ci0 = cc * CC;
    __syncthreads();
    for (int idx = tid; idx < CC * 3 * (TW + 2); idx += 256) {
      int col = idx % (TW + 2);
      int rem = idx / (TW + 2);
      int dy = rem % 3;
      int ci = rem / 3;
      int gr = (h + dy - 1 + NH) & (NH - 1);
      int gc = (w0 - 1 + col + NW) & (NW - 1);
      xt[ci][dy][col] = x[(((size_t)b * NC + ci0 + ci) * NH + gr) * NW + gc];
    }
    __syncthreads();
    for (int idx = tid; idx < CC * TW; idx += 256) {
      int ci = idx >> 7, wl = idx & (TW - 1);
      float s1 = 0.f, s2 = 0.f;
#pragma unroll
      for (int dy = 0; dy < 3; ++dy)
#pragma unroll
        for (int dx = 0; dx < 3; ++dx) {
          float v = xt[ci][dy][wl + dx];
          s1 += v;
          s2 += v * v;
        }
      snt[ci][wl] = (s1 * s1 + s2) * (0.5f / 45.0f);
    }
    __syncthreads();
    for (int ci = 0; ci < CC; ++ci) {
      const int cig = ci0 + ci;
      {
        float m = Mt[cig * NC + co];
        const float4* sp = reinterpret_cast<const float4*>(&snt[ci][wl0]);
#pragma unroll
        for (int j = 0; j < 8; ++j) {
          float4 v = sp[j];
          acc[4 * j + 0] += m * v.x;
          acc[4 * j + 1] += m * v.y;
          acc[4 * j + 2] += m * v.z;
          acc[4 * j + 3] += m * v.w;
        }
      }
      const float* wtp = Wt + cig * 9 * NC + co;
#pragma unroll
      for (int dy = 0; dy < 3; ++dy) {
        if (dy == 0 && h == 0) continue;
        if (dy == 2 && h == NH - 1) continue;
        float wv0 = wtp[(dy * 3 + 0) * NC];
        float wv1 = wtp[(dy * 3 + 1) * NC];
        float wv2 = wtp[(dy * 3 + 2) * NC];
        float xr[34];
        const float4* rp = reinterpret_cast<const float4*>(&xt[ci][dy][wl0]);
#pragma unroll
        for (int j = 0; j < 8; ++j) {
          float4 v = rp[j];
          xr[4 * j + 0] = v.x;
          xr[4 * j + 1] = v.y;
          xr[4 * j + 2] = v.z;
          xr[4 * j + 3] = v.w;
        }
        xr[32] = xt[ci][dy][wl0 + 32];
        xr[33] = xt[ci][dy][wl0 + 33];
        if (fix_lo) xr[0] = 0.f;
        if (fix_hi) xr[33] = 0.f;
#pragma unroll
        for (int k = 0; k < 32; ++k) {
          acc[k] += wv0 * xr[k] + wv1 * xr[k + 1] + wv2 * xr[k + 2];
        }
      }
    }
  }
  float* op = out + (((size_t)b * NC + co) * NH + h) * NW + w0 + wl0;
#pragma unroll
  for (int j = 0; j < 8; ++j) {
    float4 v;
    v.x = acc[4 * j + 0];
    v.y = acc[4 * j + 1];
    v.z = acc[4 * j + 2];
    v.w = acc[4 * j + 3];
    reinterpret_cast<float4*>(op)[j] = v;
  }
}

extern "C" void kernel_launch(void* const* d_in, const int* in_sizes, int n_in,
                              void* d_out, int out_size, void* d_ws, size_t ws_size,
                              hipStream_t stream) {
  const float* x = (const float*)d_in[0];
  const float* lw = (const float*)d_in[1];
  const float* lb = (const float*)d_in[2];
  const float* w2a_w = (const float*)d_in[3];
  const float* w2a_b = (const float*)d_in[4];
  const float* w2b_w = (const float*)d_in[5];
  const float* w2b_b = (const float*)d_in[6];
  float* out = (float*)d_out;

  if (ws_size >= WS_NEEDED) {
    char* ws = (char*)d_ws;
    unsigned short* xT = (unsigned short*)(ws);
    unsigned short* snT = (unsigned short*)(ws + 67108864);
    unsigned short* Wf = (unsigned short*)(ws + 134217728);
    float* bias = (float*)(ws + 134299648);
    prep_fast<<<64, 256, 0, stream>>>(lw, lb, w2a_w, w2a_b, w2b_w, w2b_b, Wf, bias);
    stage1<<<2048, 512, 0, stream>>>(x, xT, snT);
    stage2<<<2048, 256, 0, stream>>>(xT, snT, Wf, bias, out);
  } else {
    float* ws = (float*)d_ws;
    float* Mt = ws;
    float* bias2 = ws + 4096;
    float* Wt = ws + 4096 + 64;
    prep_kernel<<<1, 256, 0, stream>>>(lw, w2a_w, w2a_b, w2b_w, w2b_b, Mt, bias2, Wt);
    dim3 grid(NW / TW, NH, NB);
    volterra_main<<<grid, 256, 0, stream>>>(x, lb, Mt, bias2, Wt, out);
  }
}